// Round 10
// baseline (321.656 us; speedup 1.0000x reference)
//
#include <hip/hip_runtime.h>
#include <hip/hip_cooperative_groups.h>

namespace cg = cooperative_groups;

#define N_NODES 100000
#define N_EDGES 1600000
#define NFEAT 128
#define NHID 64

#define BBITS 8                                  // bucket = row >> 8 (256 rows)
#define NBUCK 391                                // ceil(100000 / 256)
#define BATCH 4096                               // edges per bin batch
#define NBATCH 391                               // edge batches
#define NTILE 782                                // gemm tiles (128 nodes each)
#define NREP 4                                   // cursor replicas per bucket
#define RSTRIDE 1536                             // records per replica span
#define HCAP 2560                                // LDS cap per half-bucket
#define CMASK 0x1FFFF                            // 17 bits for col
#define XPITCH 136                               // padded LDS pitch (shorts)
#define SH_BYTES 52224                           // shared union size

typedef __attribute__((ext_vector_type(8))) short short8;
typedef __attribute__((ext_vector_type(4))) float f32x4;

// fp32 -> bf16 round-to-nearest-even
__device__ __forceinline__ unsigned short f2bf(float f) {
  unsigned u = __float_as_uint(f);
  u += 0x7fffu + ((u >> 16) & 1u);
  return (unsigned short)(u >> 16);
}

// Threefry-2x32 (JAX partitionable), key (0,42)
__device__ __forceinline__ unsigned rotl32(unsigned v, int r) {
  return (v << r) | (v >> (32 - r));
}

__device__ __forceinline__ unsigned threefry_draw(unsigned i) {
  const unsigned ks0 = 0u;
  const unsigned ks1 = 42u;
  const unsigned ks2 = 0x1BD11BDAu ^ 42u;
  unsigned x0 = 0u + ks0;
  unsigned x1 = i + ks1;
#define TF_ROUND(r) { x0 += x1; x1 = rotl32(x1, (r)); x1 ^= x0; }
  TF_ROUND(13) TF_ROUND(15) TF_ROUND(26) TF_ROUND(6)
  x0 += ks1; x1 += ks2 + 1u;
  TF_ROUND(17) TF_ROUND(29) TF_ROUND(16) TF_ROUND(24)
  x0 += ks2; x1 += ks0 + 2u;
  TF_ROUND(13) TF_ROUND(15) TF_ROUND(26) TF_ROUND(6)
  x0 += ks0; x1 += ks1 + 3u;
  TF_ROUND(17) TF_ROUND(29) TF_ROUND(16) TF_ROUND(24)
  x0 += ks1; x1 += ks2 + 4u;
  TF_ROUND(13) TF_ROUND(15) TF_ROUND(26) TF_ROUND(6)
  x0 += ks2; x1 += ks0 + 5u;
#undef TF_ROUND
  return x0 ^ x1;
}

__global__ void __launch_bounds__(512, 6) gcn_mega(
    const float* __restrict__ x, const int* __restrict__ erow,
    const int* __restrict__ ecol, const float* __restrict__ eval_,
    const float* __restrict__ W, const float* __restrict__ bias_g,
    float* __restrict__ out, unsigned short* __restrict__ support_h,
    int* __restrict__ cursor, int2* __restrict__ eg) {
  __shared__ __align__(16) char shraw[SH_BYTES];
  const int t = threadIdx.x;
  cg::grid_group grid = cg::this_grid();

  // ============ Phase 1: pooled {gemm tiles} U {bin batches} ============
  for (int u = blockIdx.x; u < NTILE + NBATCH; u += gridDim.x) {
    __syncthreads();
    if (u < NTILE) {
      // ---- GEMM tile: support[node0..node0+128) = x @ W (MFMA bf16) ----
      unsigned short* xbf = (unsigned short*)shraw;            // 128*136*2 = 34816
      unsigned short* wtb = (unsigned short*)(shraw + 34816);  //  64*136*2 = 17408
      const int node0 = u * 128;
      for (int i = t; i < NHID * NFEAT; i += 512) {  // W coalesced -> wtb[n][k]
        const int k = i >> 6;
        const int n = i & 63;
        wtb[n * XPITCH + k] = f2bf(W[i]);
      }
      const int limf4 = min(128, N_NODES - node0) * 32;
      const float4* gx = (const float4*)(x + (size_t)node0 * NFEAT);
      for (int i = t; i < 128 * 32; i += 512) {
        if (i < limf4) {
          const float4 v = gx[i];
          ushort4 o;
          o.x = f2bf(v.x); o.y = f2bf(v.y); o.z = f2bf(v.z); o.w = f2bf(v.w);
          *(ushort4*)(xbf + (i >> 5) * XPITCH + (i & 31) * 4) = o;
        }
      }
      __syncthreads();
      const int wv = t >> 6;
      const int lane = t & 63;
      const int quad = lane >> 4;
      const int nl = lane & 15;
      const int mrow = wv * 16 + nl;
      f32x4 acc[4];
#pragma unroll
      for (int nt = 0; nt < 4; ++nt)
#pragma unroll
        for (int r = 0; r < 4; ++r) acc[nt][r] = 0.f;
#pragma unroll
      for (int kc = 0; kc < 4; ++kc) {
        const short8 a = *(const short8*)(xbf + mrow * XPITCH + kc * 32 + quad * 8);
#pragma unroll
        for (int nt = 0; nt < 4; ++nt) {
          const short8 bf = *(const short8*)(wtb + (nt * 16 + nl) * XPITCH +
                                             kc * 32 + quad * 8);
          acc[nt] = __builtin_amdgcn_mfma_f32_16x16x32_bf16(a, bf, acc[nt], 0, 0, 0);
        }
      }
#pragma unroll
      for (int nt = 0; nt < 4; ++nt)
#pragma unroll
        for (int r = 0; r < 4; ++r) {
          const int node = node0 + wv * 16 + quad * 4 + r;
          if (node < N_NODES)
            support_h[(size_t)node * NHID + nt * 16 + nl] = f2bf(acc[nt][r]);
        }
    } else {
      // ---- bin batch: bucket-bin 4096 edges into replica spans ----
      int* h    = (int*)shraw;              // 391 counts -> dest_base
      int* ofs  = (int*)(shraw + 1568);
      int* wsum = (int*)(shraw + 3136);
      int* spx  = (int*)(shraw + 3168);     // 4096 ints
      int* sv   = (int*)(shraw + 19552);    // 4096 ints
      short* sb = (short*)(shraw + 35936);  // 4096 shorts
      const int bidx = u - NTILE;
      const int rep = bidx & (NREP - 1);
      if (t < NBUCK) h[t] = 0;
      __syncthreads();
      const int base = bidx * BATCH;
      const int n = min(BATCH, N_EDGES - base);
      int mypx[8], myv[8], myrank[8], myb[8];
#pragma unroll
      for (int v = 0; v < 8; ++v) {
        const int j = t + v * 512;
        if (j < n) {
          const int r = erow[base + j];
          mypx[v] = ((r & 255) << 17) | ecol[base + j];
          myv[v] = __float_as_int(eval_[base + j]);
          myb[v] = r >> BBITS;
          myrank[v] = atomicAdd(&h[myb[v]], 1);
        }
      }
      __syncthreads();
      // wave-shfl exclusive scan of h[0..NBUCK)
      const int hv = (t < NBUCK) ? h[t] : 0;
      const int lane = t & 63;
      int v = hv;
#pragma unroll
      for (int off = 1; off < 64; off <<= 1) {
        const int uu = __shfl_up(v, off);
        if (lane >= off) v += uu;
      }
      if (lane == 63) wsum[t >> 6] = v;
      __syncthreads();
      int wbase = 0;
      const int mywv = t >> 6;
      for (int w = 0; w < mywv; ++w) wbase += wsum[w];
      const int my_ofs = wbase + v - hv;
      if (t < NBUCK) {
        ofs[t] = my_ofs;
        const int c = hv;
        if (c > 0) {
          const int old = atomicAdd(&cursor[(t * NREP + rep) * 16], c);
          h[t] = (t * NREP + rep) * RSTRIDE + old - my_ofs;
        }
      }
      __syncthreads();
#pragma unroll
      for (int vv = 0; vv < 8; ++vv) {
        const int j = t + vv * 512;
        if (j < n) {
          const int pos = ofs[myb[vv]] + myrank[vv];
          spx[pos] = mypx[vv];
          sv[pos] = myv[vv];
          sb[pos] = (short)myb[vv];
        }
      }
      __syncthreads();
      for (int j = t; j < n; j += 512) {
        const int d = h[sb[j]] + j;
        eg[d] = make_int2(spx[j], sv[j]);
      }
    }
    __syncthreads();
  }

  grid.sync();

  // ============ Phase 2: rowagg (fused rowsort-to-LDS + aggregate) ============
  for (int u = blockIdx.x; u < 2 * NBUCK; u += gridDim.x) {
    __syncthreads();
    int2* srec  = (int2*)shraw;             // 2560 int2 = 20480
    int* cnt    = (int*)(shraw + 20480);    // 128
    int* rstart = (int*)(shraw + 20992);    // 128
    const int k = u >> 1;
    const int half = u & 1;
    if (t < 128) cnt[t] = 0;
    __syncthreads();
    int px[12], pv[12], rk[12];
    int idx = 0;
#pragma unroll
    for (int rep = 0; rep < NREP; ++rep) {
      const int span = k * NREP + rep;
      const int n = cursor[span * 16];
      const int sbase = span * RSTRIDE;
#pragma unroll
      for (int uu = 0; uu < 3; ++uu, ++idx) {
        const int j = t + uu * 512;
        const bool ok = j < n;
        int2 p = make_int2(0, 0);
        if (ok) p = eg[sbase + j];
        px[idx] = p.x;
        pv[idx] = p.y;
        const int r = ((unsigned)p.x) >> 17;
        rk[idx] = (ok && ((r >> 7) == half)) ? atomicAdd(&cnt[r & 127], 1) : -1;
      }
    }
    __syncthreads();
    if (t < 64) {
      const int a0 = cnt[t];
      const int a1 = cnt[64 + t];
      int s0 = a0;
#pragma unroll
      for (int off = 1; off < 64; off <<= 1) {
        const int uu = __shfl_up(s0, off);
        if (t >= off) s0 += uu;
      }
      const int tot0 = __shfl(s0, 63);
      int s1 = a1;
#pragma unroll
      for (int off = 1; off < 64; off <<= 1) {
        const int uu = __shfl_up(s1, off);
        if (t >= off) s1 += uu;
      }
      rstart[t] = s0 - a0;
      rstart[64 + t] = tot0 + s1 - a1;
    }
    __syncthreads();
#pragma unroll
    for (int uu = 0; uu < 12; ++uu) {
      if (rk[uu] >= 0) {
        const int r = (((unsigned)px[uu]) >> 17) & 127;
        srec[rstart[r] + rk[uu]] = make_int2(px[uu] & CMASK, pv[uu]);
      }
    }
    __syncthreads();
    const int wv = t >> 6;
    const int lane = t & 63;
    const int grp = lane >> 3;
    const int sub = lane & 7;
    const int feat = (sub << 3) | grp;
    const float bias = bias_g[feat];
    for (int rr = 0; rr < 16; ++rr) {
      const int r = wv * 16 + rr;
      const int node = (k << BBITS) + (half << 7) + r;
      if (node >= N_NODES) break;  // wave-uniform
      const int s = rstart[r];
      const int e = s + cnt[r];
      float acc[8];
#pragma unroll
      for (int j = 0; j < 8; ++j) acc[j] = 0.f;
      for (int i = s; i < e; i += 8) {
        const int ii = i + grp;
        int2 p = make_int2(0, 0);
        if (ii < e) p = srec[ii];
        const uint4 q = ((const uint4*)support_h)[(size_t)p.x * 8 + sub];
        const float v = __int_as_float(p.y);
        acc[0] = __builtin_fmaf(v, __uint_as_float(q.x << 16), acc[0]);
        acc[1] = __builtin_fmaf(v, __uint_as_float(q.x & 0xffff0000u), acc[1]);
        acc[2] = __builtin_fmaf(v, __uint_as_float(q.y << 16), acc[2]);
        acc[3] = __builtin_fmaf(v, __uint_as_float(q.y & 0xffff0000u), acc[3]);
        acc[4] = __builtin_fmaf(v, __uint_as_float(q.z << 16), acc[4]);
        acc[5] = __builtin_fmaf(v, __uint_as_float(q.z & 0xffff0000u), acc[5]);
        acc[6] = __builtin_fmaf(v, __uint_as_float(q.w << 16), acc[6]);
        acc[7] = __builtin_fmaf(v, __uint_as_float(q.w & 0xffff0000u), acc[7]);
      }
      const int g0 = grp & 1, g1 = (grp >> 1) & 1, g2 = grp >> 2;
      float v4[4];
#pragma unroll
      for (int i = 0; i < 4; ++i) {
        const float keep = g0 ? acc[2 * i + 1] : acc[2 * i];
        const float give = g0 ? acc[2 * i] : acc[2 * i + 1];
        v4[i] = keep + __shfl_xor(give, 8);
      }
      float v2[2];
#pragma unroll
      for (int i = 0; i < 2; ++i) {
        const float keep = g1 ? v4[2 * i + 1] : v4[2 * i];
        const float give = g1 ? v4[2 * i] : v4[2 * i + 1];
        v2[i] = keep + __shfl_xor(give, 16);
      }
      const float keep = g2 ? v2[1] : v2[0];
      const float give = g2 ? v2[0] : v2[1];
      const float aval = keep + __shfl_xor(give, 32);
      const float h = fmaxf(aval + bias, 0.f);
      const unsigned idxg = (unsigned)node * 64u + (unsigned)feat;
      const bool keepm = (threefry_draw(idxg) >> 31) == 0u;
      out[idxg] = keepm ? h * 2.0f : 0.0f;
    }
    __syncthreads();
  }
}

extern "C" void kernel_launch(void* const* d_in, const int* in_sizes, int n_in,
                              void* d_out, int out_size, void* d_ws, size_t ws_size,
                              hipStream_t stream) {
  const float* x     = (const float*)d_in[0];
  const int*   erow  = (const int*)d_in[1];
  const int*   ecol  = (const int*)d_in[2];
  const float* eval_ = (const float*)d_in[3];
  const float* W     = (const float*)d_in[4];
  const float* b     = (const float*)d_in[5];
  float* out = (float*)d_out;

  // Workspace layout (bytes), total ~32.1 MB:
  char* ws = (char*)d_ws;
  unsigned short* support_h = (unsigned short*)(ws);  // 12,800,000 (bf16)
  int*  cursor = (int*)(ws + 12800000);               //    100,096 (1564 x 64B)
  int2* eg     = (int2*)(ws + 12900096);              // 19,218,432 (1564 x 1536 x 8)

  hipMemsetAsync(cursor, 0, NBUCK * NREP * 16 * sizeof(int), stream);

  int maxb = 0;
  hipOccupancyMaxActiveBlocksPerMultiprocessor(&maxb, (const void*)gcn_mega, 512, 0);
  if (maxb < 1) maxb = 1;
  if (maxb > 3) maxb = 3;
  const int grid = maxb * 256;

  void* args[] = {(void*)&x, (void*)&erow, (void*)&ecol, (void*)&eval_,
                  (void*)&W, (void*)&b, (void*)&out, (void*)&support_h,
                  (void*)&cursor, (void*)&eg};
  hipLaunchCooperativeKernel((const void*)gcn_mega, dim3(grid), dim3(512),
                             args, 0, stream);
}

// Round 11
// 179.356 us; speedup vs baseline: 1.7934x; 1.7934x over previous
//
#include <hip/hip_runtime.h>

#define N_NODES 100000
#define N_EDGES 1600000
#define NFEAT 128
#define NHID 64

#define BBITS 8                                  // bucket = row >> 8 (256 rows)
#define NBUCK 391                                // ceil(100000 / 256)
#define BATCH 4096                               // edges per bin block
#define NBATCH 391                               // edge batches
#define NREP 4                                   // cursor replicas per bucket
#define RSTRIDE 1536                             // records per replica span
#define QCAP 1408                                // LDS cap per quarter-bucket (mean 1024 + 12 sigma)
#define CMASK 0x1FFFF                            // 17 bits for col
#define XP 132                                   // LDS pitch in shorts (bank-stride 2)

typedef __attribute__((ext_vector_type(8))) short short8;
typedef __attribute__((ext_vector_type(4))) float f32x4;

// fp32 -> bf16 round-to-nearest-even
__device__ __forceinline__ unsigned short f2bf(float f) {
  unsigned u = __float_as_uint(f);
  u += 0x7fffu + ((u >> 16) & 1u);
  return (unsigned short)(u >> 16);
}

// ---------------- GEMM: support = x @ W via MFMA bf16 (W staged per block) ----
// 256 threads, 64 nodes/block, grid 1563. Block 0 also inits cursors.
__global__ __launch_bounds__(256) void gcn_gemm(const float* __restrict__ x,
                                                const float* __restrict__ W,
                                                unsigned short* __restrict__ support_h,
                                                int* __restrict__ cursor) {
  __shared__ unsigned short xbf[64 * XP];   // 16,896 B
  __shared__ unsigned short wtb[64 * XP];   // 16,896 B
  const int t = threadIdx.x;
  if (blockIdx.x == 0)
    for (int i = t; i < NBUCK * NREP; i += 256) cursor[i * 16] = 0;
  // stage W^T as bf16: wtb[n][k]
  for (int i = t; i < NHID * NFEAT; i += 256) {   // i = k*64 + n (coalesced)
    const int k = i >> 6;
    const int n = i & 63;
    wtb[n * XP + k] = f2bf(W[i]);
  }
  // stage x tile as bf16: xbf[row][k]
  const int node0 = blockIdx.x * 64;
  const float4* __restrict__ gx = (const float4*)(x + (size_t)node0 * NFEAT);
  const int limf4 = min(64, N_NODES - node0) * 32;
  for (int i = t; i < 64 * 32; i += 256) {
    if (i < limf4) {
      const float4 v = gx[i];
      ushort4 o;
      o.x = f2bf(v.x); o.y = f2bf(v.y); o.z = f2bf(v.z); o.w = f2bf(v.w);
      *(ushort4*)(xbf + (i >> 5) * XP + (i & 31) * 4) = o;
    }
  }
  __syncthreads();
  const int wv = t >> 6;
  const int lane = t & 63;
  const int quad = lane >> 4;
  const int nl = lane & 15;
  const int mrow = wv * 16 + nl;
  f32x4 acc[4];
#pragma unroll
  for (int nt = 0; nt < 4; ++nt)
#pragma unroll
    for (int r = 0; r < 4; ++r) acc[nt][r] = 0.f;
#pragma unroll
  for (int kc = 0; kc < 4; ++kc) {
    const short8 a = *(const short8*)(xbf + mrow * XP + kc * 32 + quad * 8);
#pragma unroll
    for (int nt = 0; nt < 4; ++nt) {
      const short8 bf = *(const short8*)(wtb + (nt * 16 + nl) * XP + kc * 32 + quad * 8);
      acc[nt] = __builtin_amdgcn_mfma_f32_16x16x32_bf16(a, bf, acc[nt], 0, 0, 0);
    }
  }
#pragma unroll
  for (int nt = 0; nt < 4; ++nt)
#pragma unroll
    for (int r = 0; r < 4; ++r) {
      const int node = node0 + wv * 16 + quad * 4 + r;
      if (node < N_NODES)
        support_h[(size_t)node * NHID + nt * 16 + nl] = f2bf(acc[nt][r]);
    }
}

// ---------------- bin: bucket-bin edges into replica spans (R9-proven) --------
// eg[i] = { (r&255)<<17 | c , float_bits(val) }. Span s = bucket*NREP + rep.
__global__ __launch_bounds__(512) void gcn_bin(const int* __restrict__ erow,
                                               const int* __restrict__ ecol,
                                               const float* __restrict__ eval_,
                                               int* __restrict__ cursor,
                                               int2* __restrict__ eg) {
  __shared__ int h[NBUCK];       // counts, then dest_base
  __shared__ int ofs[NBUCK];
  __shared__ int wsum[8];
  __shared__ int spx[BATCH];
  __shared__ int sv[BATCH];
  __shared__ short sb[BATCH];
  const int t = threadIdx.x;
  const int rep = blockIdx.x & (NREP - 1);
  if (t < NBUCK) h[t] = 0;
  __syncthreads();
  const int base = blockIdx.x * BATCH;
  const int n = min(BATCH, N_EDGES - base);
  int mypx[8], myv[8], myrank[8], myb[8];
#pragma unroll
  for (int u = 0; u < 8; ++u) {
    const int j = t + u * 512;
    if (j < n) {
      const int r = erow[base + j];
      mypx[u] = ((r & 255) << 17) | ecol[base + j];
      myv[u] = __float_as_int(eval_[base + j]);
      myb[u] = r >> BBITS;
      myrank[u] = atomicAdd(&h[myb[u]], 1);
    }
  }
  __syncthreads();
  // wave-shfl exclusive scan of h[0..NBUCK) -> ofs
  const int hv = (t < NBUCK) ? h[t] : 0;
  const int lane = t & 63;
  int v = hv;
#pragma unroll
  for (int off = 1; off < 64; off <<= 1) {
    const int u = __shfl_up(v, off);
    if (lane >= off) v += u;
  }
  if (lane == 63) wsum[t >> 6] = v;
  __syncthreads();
  int wbase = 0;
  const int mywv = t >> 6;
  for (int w = 0; w < mywv; ++w) wbase += wsum[w];
  const int my_ofs = wbase + v - hv;  // exclusive
  if (t < NBUCK) {
    ofs[t] = my_ofs;
    const int c = hv;
    if (c > 0) {
      const int old = atomicAdd(&cursor[(t * NREP + rep) * 16], c);
      h[t] = (t * NREP + rep) * RSTRIDE + old - my_ofs;  // dest_base - local_ofs
    }
  }
  __syncthreads();
#pragma unroll
  for (int u = 0; u < 8; ++u) {
    const int j = t + u * 512;
    if (j < n) {
      const int pos = ofs[myb[u]] + myrank[u];
      spx[pos] = mypx[u];
      sv[pos] = myv[u];
      sb[pos] = (short)myb[u];
    }
  }
  __syncthreads();
  for (int j = t; j < n; j += 512) {
    const int d = h[sb[j]] + j;   // consecutive j in same bucket -> consecutive d
    eg[d] = make_int2(spx[j], sv[j]);
  }
}

// ---------------- Threefry-2x32 (JAX partitionable), key (0,42) ----------------
__device__ __forceinline__ unsigned rotl32(unsigned v, int r) {
  return (v << r) | (v >> (32 - r));
}

__device__ __forceinline__ unsigned threefry_draw(unsigned i) {
  const unsigned ks0 = 0u;
  const unsigned ks1 = 42u;
  const unsigned ks2 = 0x1BD11BDAu ^ 42u;
  unsigned x0 = 0u + ks0;
  unsigned x1 = i + ks1;
#define TF_ROUND(r) { x0 += x1; x1 = rotl32(x1, (r)); x1 ^= x0; }
  TF_ROUND(13) TF_ROUND(15) TF_ROUND(26) TF_ROUND(6)
  x0 += ks1; x1 += ks2 + 1u;
  TF_ROUND(17) TF_ROUND(29) TF_ROUND(16) TF_ROUND(24)
  x0 += ks2; x1 += ks0 + 2u;
  TF_ROUND(13) TF_ROUND(15) TF_ROUND(26) TF_ROUND(6)
  x0 += ks0; x1 += ks1 + 3u;
  TF_ROUND(17) TF_ROUND(29) TF_ROUND(16) TF_ROUND(24)
  x0 += ks1; x1 += ks2 + 4u;
  TF_ROUND(13) TF_ROUND(15) TF_ROUND(26) TF_ROUND(6)
  x0 += ks2; x1 += ks0 + 5u;
#undef TF_ROUND
  return x0 ^ x1;
}

// ---------------- rowagg: fused rowsort (to LDS) + aggregate, quarter-split ---
// Grid 4*NBUCK; block handles 64 rows (quarter = blockIdx&3) of bucket blockIdx>>2.
__global__ __launch_bounds__(512) void gcn_rowagg(const int* __restrict__ cursor,
                                                  const int2* __restrict__ eg,
                                                  const unsigned short* __restrict__ support_h,
                                                  const float* __restrict__ b,
                                                  float* __restrict__ out) {
  __shared__ int2 srec[QCAP];    // 11,264 B row-sorted records
  __shared__ int cnt[64];
  __shared__ int rstart[64];
  const int t = threadIdx.x;
  const int k = blockIdx.x >> 2;
  const int qtr = blockIdx.x & 3;
  if (t < 64) cnt[t] = 0;
  __syncthreads();
  // phase 1: register-load the bucket's 4 replica spans, keep-filter, rank
  int px[12], pv[12], rk[12];
  int idx = 0;
#pragma unroll
  for (int rep = 0; rep < NREP; ++rep) {
    const int span = k * NREP + rep;
    const int n = cursor[span * 16];
    const int sbase = span * RSTRIDE;
#pragma unroll
    for (int u = 0; u < 3; ++u, ++idx) {
      const int j = t + u * 512;
      const bool ok = j < n;
      int2 p = make_int2(0, 0);
      if (ok) p = eg[sbase + j];
      px[idx] = p.x;
      pv[idx] = p.y;
      const int r = ((unsigned)p.x) >> 17;
      rk[idx] = (ok && ((r >> 6) == qtr)) ? atomicAdd(&cnt[r & 63], 1) : -1;
    }
  }
  __syncthreads();
  // wave-0 scan of cnt[64] -> rstart
  if (t < 64) {
    const int a = cnt[t];
    int s = a;
#pragma unroll
    for (int off = 1; off < 64; off <<= 1) {
      const int u = __shfl_up(s, off);
      if (t >= off) s += u;
    }
    rstart[t] = s - a;
  }
  __syncthreads();
  // scatter kept records into LDS, sorted by row
#pragma unroll
  for (int u = 0; u < 12; ++u) {
    if (rk[u] >= 0) {
      const int r = (((unsigned)px[u]) >> 17) & 63;
      srec[rstart[r] + rk[u]] = make_int2(px[u] & CMASK, pv[u]);
    }
  }
  __syncthreads();
  // phase 2: aggregate 8 waves x 8 rows, 8 edges in flight, butterfly RS
  const int wv = t >> 6;
  const int lane = t & 63;
  const int grp = lane >> 3;
  const int sub = lane & 7;
  const int feat = (sub << 3) | grp;
  const float bias = b[feat];
  for (int rr = 0; rr < 8; ++rr) {
    const int r = wv * 8 + rr;
    const int node = (k << BBITS) + (qtr << 6) + r;
    if (node >= N_NODES) break;  // wave-uniform
    const int s = rstart[r];
    const int e = s + cnt[r];
    float acc[8];
#pragma unroll
    for (int j = 0; j < 8; ++j) acc[j] = 0.f;
    for (int i = s; i < e; i += 8) {
      const int ii = i + grp;
      int2 p = make_int2(0, 0);
      if (ii < e) p = srec[ii];
      const uint4 q = ((const uint4*)support_h)[(size_t)p.x * 8 + sub];
      const float v = __int_as_float(p.y);
      acc[0] = __builtin_fmaf(v, __uint_as_float(q.x << 16), acc[0]);
      acc[1] = __builtin_fmaf(v, __uint_as_float(q.x & 0xffff0000u), acc[1]);
      acc[2] = __builtin_fmaf(v, __uint_as_float(q.y << 16), acc[2]);
      acc[3] = __builtin_fmaf(v, __uint_as_float(q.y & 0xffff0000u), acc[3]);
      acc[4] = __builtin_fmaf(v, __uint_as_float(q.z << 16), acc[4]);
      acc[5] = __builtin_fmaf(v, __uint_as_float(q.z & 0xffff0000u), acc[5]);
      acc[6] = __builtin_fmaf(v, __uint_as_float(q.w << 16), acc[6]);
      acc[7] = __builtin_fmaf(v, __uint_as_float(q.w & 0xffff0000u), acc[7]);
    }
    // butterfly reduce-scatter over grp bits, keeping j = grp
    const int g0 = grp & 1, g1 = (grp >> 1) & 1, g2 = grp >> 2;
    float v4[4];
#pragma unroll
    for (int i = 0; i < 4; ++i) {
      const float keep = g0 ? acc[2 * i + 1] : acc[2 * i];
      const float give = g0 ? acc[2 * i] : acc[2 * i + 1];
      v4[i] = keep + __shfl_xor(give, 8);
    }
    float v2[2];
#pragma unroll
    for (int i = 0; i < 2; ++i) {
      const float keep = g1 ? v4[2 * i + 1] : v4[2 * i];
      const float give = g1 ? v4[2 * i] : v4[2 * i + 1];
      v2[i] = keep + __shfl_xor(give, 16);
    }
    const float keep = g2 ? v2[1] : v2[0];
    const float give = g2 ? v2[0] : v2[1];
    const float aval = keep + __shfl_xor(give, 32);
    const float h = fmaxf(aval + bias, 0.f);
    const unsigned idxg = (unsigned)node * 64u + (unsigned)feat;
    const bool keepm = (threefry_draw(idxg) >> 31) == 0u;
    out[idxg] = keepm ? h * 2.0f : 0.0f;
  }
}

extern "C" void kernel_launch(void* const* d_in, const int* in_sizes, int n_in,
                              void* d_out, int out_size, void* d_ws, size_t ws_size,
                              hipStream_t stream) {
  const float* x     = (const float*)d_in[0];
  const int*   erow  = (const int*)d_in[1];
  const int*   ecol  = (const int*)d_in[2];
  const float* eval_ = (const float*)d_in[3];
  const float* W     = (const float*)d_in[4];
  const float* b     = (const float*)d_in[5];
  float* out = (float*)d_out;

  // Workspace layout (bytes), total ~32.1 MB:
  char* ws = (char*)d_ws;
  unsigned short* support_h = (unsigned short*)(ws);  // 12,800,000 (bf16)
  int*  cursor = (int*)(ws + 12800000);               //    100,096 (1564 x 64B)
  int2* eg     = (int2*)(ws + 12900096);              // 19,218,432 (1564 x 1536 x 8)

  hipLaunchKernelGGL(gcn_gemm, dim3((N_NODES + 63) / 64), dim3(256), 0, stream,
                     x, W, support_h, cursor);
  hipLaunchKernelGGL(gcn_bin, dim3(NBATCH), dim3(512), 0, stream,
                     erow, ecol, eval_, cursor, eg);
  hipLaunchKernelGGL(gcn_rowagg, dim3(4 * NBUCK), dim3(512), 0, stream,
                     cursor, eg, support_h, b, out);
}